// Round 11
// baseline (1107.273 us; speedup 1.0000x reference)
//
#include <hip/hip_runtime.h>
#include <hip/hip_bf16.h>

#define E_ 16
#define D_ 4096
#define F_ 688
#define N_ 8192
#define CAP_ 640     // int(1.25 * 8192 / 16)
#define NFT_ 11      // 64-f tiles
#define NKT32_ 128   // D/32 k-tiles
#define NFT32_ 22    // ceil(F/32) f-tiles (pad to 704)

typedef __attribute__((ext_vector_type(8))) short bf16x8;
typedef __attribute__((ext_vector_type(4))) float f32x4;
typedef __attribute__((ext_vector_type(4))) float fvec4;
typedef __attribute__((ext_vector_type(4))) unsigned short usvec4;
typedef __attribute__((ext_vector_type(8))) unsigned short usvec8;

__device__ __forceinline__ unsigned short f2bf(float f) {
    __hip_bfloat16 h = __float2bfloat16(f);
    return __builtin_bit_cast(unsigned short, h);
}
// async global->LDS, 16B per lane
__device__ __forceinline__ void gload16(const unsigned short* g, unsigned short* l) {
    __builtin_amdgcn_global_load_lds(
        (const __attribute__((address_space(1))) unsigned int*)g,
        (__attribute__((address_space(3))) unsigned int*)l, 16, 0, 0);
}

#define WAITVN(N) asm volatile("s_waitcnt vmcnt(" #N ")" ::: "memory")
#define SBAR      __builtin_amdgcn_s_barrier()
#define SCHED0    __builtin_amdgcn_sched_barrier(0)

// Tile layouts (k-major, conflict-free):
//   A-tile (128 rows x 32 k):  [kgroup 4][row 128][8 bf16] = 4096 elems
//   B-tile ( 64 rows x 32 k):  [kgroup 4][row  64][8 bf16] = 2048 elems
// Waves are (wm, kh): each wave owns 64 rows x ALL cols x half of each BK=64
// step -> A read exactly once per block (no wn replication). K-halves are
// reduced across the kh-pair at epilogue via LDS.

// ---------------- dispatch ----------------
__global__ void k_dispatch(const int* __restrict__ idx,
                           int* __restrict__ slot_token,
                           int* __restrict__ row_of,
                           int* __restrict__ cnt) {
    __shared__ int hist[256][E_];
    const int t = threadIdx.x;
#pragma unroll
    for (int e = 0; e < E_; e++) hist[t][e] = 0;
    __syncthreads();
    const int base = t * (N_ / 256);
    for (int j = 0; j < N_ / 256; j++) {
        int e = idx[base + j];
        hist[t][e]++;
    }
    __syncthreads();
    if (t < E_) {
        int run = 0;
        for (int i = 0; i < 256; i++) { int v = hist[i][t]; hist[i][t] = run; run += v; }
        cnt[t] = run < CAP_ ? run : CAP_;
    }
    for (int s = t; s < E_ * CAP_; s += 256) slot_token[s] = -1;
    __syncthreads();
    for (int j = 0; j < N_ / 256; j++) {
        int i = base + j;
        int e = idx[i];
        int p = hist[t][e]++;
        if (p < CAP_) { slot_token[e * CAP_ + p] = i; row_of[i] = e * CAP_ + p; }
        else          { row_of[i] = -1; }
    }
}

__global__ void k_zero_dropped(const int* __restrict__ row_of, float* __restrict__ y) {
    for (int i = blockIdx.x; i < N_; i += gridDim.x) {
        if (row_of[i] >= 0) continue;
        fvec4* yp = (fvec4*)(y + (size_t)i * D_);
        fvec4 z = {0.f, 0.f, 0.f, 0.f};
        for (int c = threadIdx.x; c < D_ / 4; c += 256) yp[c] = z;
    }
}

// ---------------- gather x -> Aimg (k-major 32-k tiles, bf16) ----------------
__global__ void k_gather(const float* __restrict__ x, const int* __restrict__ slot_token,
                         unsigned short* __restrict__ Aimg) {
    const int strip = blockIdx.y;       // 0..79  (= e*5 + mb)
    const int kg = blockIdx.x;          // 0..15  (8 k-tiles each)
    const int t = threadIdx.x;
    const int r = t >> 1, h = t & 1;
    const int tok = slot_token[strip * 128 + r];
#pragma unroll
    for (int i = 0; i < 8; i++) {
        const int kt = kg * 8 + i;
        unsigned short* dst = Aimg + ((size_t)strip * NKT32_ + kt) * 4096;
        usvec8 p0, p1;
        if (tok < 0) {
            usvec8 z = {0, 0, 0, 0, 0, 0, 0, 0};
            p0 = z; p1 = z;
        } else {
            const float* src = x + (size_t)tok * D_ + kt * 32 + h * 16;
            fvec4 a = *(const fvec4*)(src);
            fvec4 b = *(const fvec4*)(src + 4);
            fvec4 c = *(const fvec4*)(src + 8);
            fvec4 d = *(const fvec4*)(src + 12);
            usvec8 q0 = {f2bf(a[0]), f2bf(a[1]), f2bf(a[2]), f2bf(a[3]),
                         f2bf(b[0]), f2bf(b[1]), f2bf(b[2]), f2bf(b[3])};
            usvec8 q1 = {f2bf(c[0]), f2bf(c[1]), f2bf(c[2]), f2bf(c[3]),
                         f2bf(d[0]), f2bf(d[1]), f2bf(d[2]), f2bf(d[3])};
            p0 = q0; p1 = q1;
        }
        *(usvec8*)&dst[(2 * h) * 1024 + r * 8]     = p0;
        *(usvec8*)&dst[(2 * h + 1) * 1024 + r * 8] = p1;
    }
}

// ---------------- wprep: Wg,Wu -> [e][kt32][ft][G 2048 | U 2048] ----------------
__global__ void k_wprep_gu(const float* __restrict__ Wg, const float* __restrict__ Wu,
                           unsigned short* __restrict__ img) {
    const int ft = blockIdx.x, kt = blockIdx.y, e = blockIdx.z;   // kt: 64-k block
    const int tid = threadIdx.x;
    const int f4 = (tid & 15) * 4, kq4 = (tid >> 4) * 4;
    const int gf = ft * 64 + f4;
    const bool v = gf < F_;
    const fvec4 fz = {0.f, 0.f, 0.f, 0.f};
    fvec4 g[4], u[4];
#pragma unroll
    for (int r = 0; r < 4; r++) {
        size_t off = (size_t)e * D_ * F_ + (size_t)(kt * 64 + kq4 + r) * F_ + gf;
        g[r] = v ? *(const fvec4*)(Wg + off) : fz;
        u[r] = v ? *(const fvec4*)(Wu + off) : fz;
    }
    const int t32 = kq4 >> 5, kl = kq4 & 31;
    unsigned short* dst = img + ((size_t)(e * NKT32_ + kt * 2 + t32) * NFT_ + ft) * 4096;
    const int ubase = (kl >> 3) * 512 + (kl & 7);
#pragma unroll
    for (int i = 0; i < 4; i++) {
        usvec4 pg = {f2bf(g[0][i]), f2bf(g[1][i]), f2bf(g[2][i]), f2bf(g[3][i])};
        usvec4 pu = {f2bf(u[0][i]), f2bf(u[1][i]), f2bf(u[2][i]), f2bf(u[3][i])};
        *(usvec4*)&dst[ubase + (f4 + i) * 8]        = pg;
        *(usvec4*)&dst[2048 + ubase + (f4 + i) * 8] = pu;
    }
}

// ---------------- wprep: Wd -> [e][kt32(22)][dt(64)][2048] ----------------
__global__ void k_wprep_d(const float* __restrict__ Wd, unsigned short* __restrict__ img) {
    const int dt = blockIdx.x, kt = blockIdx.y, e = blockIdx.z;   // kt: 64-k block (0..10)
    const int tid = threadIdx.x;
    const int d4 = (tid & 15) * 4, kq4 = (tid >> 4) * 4;
    const int gd = dt * 64 + d4;
    const fvec4 fz = {0.f, 0.f, 0.f, 0.f};
    fvec4 b[4];
#pragma unroll
    for (int r = 0; r < 4; r++) {
        int krow = kt * 64 + kq4 + r;
        b[r] = (krow < F_) ? *(const fvec4*)(Wd + (size_t)e * F_ * D_ + (size_t)krow * D_ + gd) : fz;
    }
    const int t32 = kq4 >> 5, kl = kq4 & 31;
    unsigned short* dst = img + ((size_t)(e * NFT32_ + kt * 2 + t32) * 64 + dt) * 2048;
    const int ubase = (kl >> 3) * 512 + (kl & 7);
#pragma unroll
    for (int i = 0; i < 4; i++) {
        usvec4 p = {f2bf(b[0][i]), f2bf(b[1][i]), f2bf(b[2][i]), f2bf(b[3][i])};
        *(usvec4*)&dst[ubase + (d4 + i) * 8] = p;
    }
}

// ================= GEMM1: kh-split waves, A direct->regs, B 3-deep LDS DMA =================
__global__ __launch_bounds__(256, 2) void k_gemm1_dma(
    const unsigned short* __restrict__ Aimg, const unsigned short* __restrict__ Wgu,
    const int* __restrict__ cnt, unsigned short* __restrict__ Himg) {
    const int bid = blockIdx.x;           // 880 = 8 xcd * 22 groups * 5 m
    const int xcd = bid & 7;
    const int j = bid >> 3;
    const int mb = j % 5;
    const int gl = j / 5;
    const int group = xcd * 22 + gl;      // 0..175
    const int e = group / NFT_, fidx = group % NFT_;
    const int m0 = mb * 128;
    if (m0 >= cnt[e]) return;
    const int strip = e * 5 + mb;

    __shared__ __align__(16) unsigned short Bgu[3][8192];   // 48 KB -> 2 blocks/CU

    const int tid = threadIdx.x;
    const int lane = tid & 63, wave = tid >> 6;
    const int wm = wave & 1, kh = wave >> 1;

    f32x4 accG[4][4], accU[4][4];
#pragma unroll
    for (int a = 0; a < 4; a++)
#pragma unroll
        for (int b = 0; b < 4; b++) {
            f32x4 z = {0.f, 0.f, 0.f, 0.f};
            accG[a][b] = z; accU[a][b] = z;
        }

    const unsigned short* Astrip = Aimg + (size_t)strip * NKT32_ * 4096;
    const unsigned short* WguE = Wgu + ((size_t)e * NKT32_ * NFT_ + fidx) * 4096;
    const int GUS = NFT_ * 4096;          // stride between consecutive kt32 B tiles
    const int afo = (lane >> 4) * 1024 + (wm * 64 + (lane & 15)) * 8;
    const int bfo = (lane >> 4) * 512 + (lane & 15) * 8;

    bf16x8 a0[4], a1[4];

#define LOADA1(T, S)                                                             \
    {                                                                            \
        const unsigned short* ab = Astrip + (size_t)(2 * (T) + kh) * 4096 + afo; \
        _Pragma("unroll") for (int mf = 0; mf < 4; mf++)                         \
            S[mf] = *(const bf16x8*)(ab + mf * 128);                             \
    }
#define DMAB1(T, BUF)                                                            \
    {                                                                            \
        const unsigned short* bA = WguE + (size_t)(2 * (T)) * GUS;               \
        const unsigned short* bB = bA + GUS;                                     \
        _Pragma("unroll") for (int i = 0; i < 4; i++) {                          \
            const int c = wave * 4 + i;                                          \
            const unsigned short* src = (c < 8) ? (bA + c * 512) : (bB + (c - 8) * 512); \
            gload16(src + lane * 8, &Bgu[BUF][c * 512]);                         \
        }                                                                        \
    }
#define MFMAS1(BUF, S)                                                           \
    {                                                                            \
        __builtin_amdgcn_s_setprio(1);                                           \
        bf16x8 bg[4], bu[4];                                                     \
        _Pragma("unroll") for (int nf = 0; nf < 4; nf++) {                       \
            bg[nf] = *(const bf16x8*)&Bgu[BUF][kh * 4096 + bfo + nf * 128];      \
            bu[nf] = *(const bf16x8*)&Bgu[BUF][kh * 4096 + 2048 + bfo + nf * 128]; \
        }                                                                        \
        _Pragma("unroll") for (int mf = 0; mf < 4; mf++)                         \
        _Pragma("unroll") for (int nf = 0; nf < 4; nf++) {                       \
            accG[mf][nf] = __builtin_amdgcn_mfma_f32_16x16x32_bf16(S[mf], bg[nf], accG[mf][nf], 0, 0, 0); \
            accU[mf][nf] = __builtin_amdgcn_mfma_f32_16x16x32_bf16(S[mf], bu[nf], accU[mf][nf], 0, 0, 0); \
        }                                                                        \
        __builtin_amdgcn_s_setprio(0);                                           \
    }
// iter: WAITV(counted) -> SBAR publishes B(t) from ALL waves -> issue A(t+1),B(t+2) -> MFMA(t)
#define G1IT(T, CS, NS, WN, HA, HB)                                              \
    {                                                                            \
        WAITVN(WN);                                                              \
        SBAR;                                                                    \
        if (HA) { LOADA1((T) + 1, NS) }                                          \
        if (HB) { DMAB1((T) + 2, ((T) + 2) % 3) }                                \
        SCHED0;                                                                  \
        MFMAS1((T) % 3, CS)                                                      \
    }

    LOADA1(0, a0)
    SCHED0;
    DMAB1(0, 0)
    DMAB1(1, 1)
    SCHED0;

    for (int m = 0; m < 31; m++) {
        G1IT(2 * m,     a0, a1, 4, 1, 1)
        G1IT(2 * m + 1, a1, a0, 4, 1, 1)
    }
    G1IT(62, a0, a1, 4, 1, 0)
    G1IT(63, a1, a0, 0, 0, 0)
#undef G1IT
#undef MFMAS1
#undef DMAB1
#undef LOADA1

    // ---- cross-wave K-half reduction (Bgu reused as f32 scratch, 32 KB/round) ----
    {
        float* red = (float*)(&Bgu[0][0]);
        __syncthreads();
#pragma unroll
        for (int mf = 0; mf < 4; mf++)
#pragma unroll
            for (int nfl = 0; nfl < 2; nfl++)
                *(f32x4*)&red[(((wm * 2 + (1 - kh)) * 4 + mf) * 2 + nfl) * 256 + lane * 4] =
                    accG[mf][2 * (1 - kh) + nfl];
        __syncthreads();
#pragma unroll
        for (int mf = 0; mf < 4; mf++)
#pragma unroll
            for (int nfl = 0; nfl < 2; nfl++) {
                f32x4 p = *(const f32x4*)&red[(((wm * 2 + kh) * 4 + mf) * 2 + nfl) * 256 + lane * 4];
                accG[mf][2 * kh + nfl] += p;
            }
        __syncthreads();
#pragma unroll
        for (int mf = 0; mf < 4; mf++)
#pragma unroll
            for (int nfl = 0; nfl < 2; nfl++)
                *(f32x4*)&red[(((wm * 2 + (1 - kh)) * 4 + mf) * 2 + nfl) * 256 + lane * 4] =
                    accU[mf][2 * (1 - kh) + nfl];
        __syncthreads();
#pragma unroll
        for (int mf = 0; mf < 4; mf++)
#pragma unroll
            for (int nfl = 0; nfl < 2; nfl++) {
                f32x4 p = *(const f32x4*)&red[(((wm * 2 + kh) * 4 + mf) * 2 + nfl) * 256 + lane * 4];
                accU[mf][2 * kh + nfl] += p;
            }
    }

    // ---- epilogue: fused SwiGLU -> Himg; wave owns cols (2kh+nfl)*16 ----
    unsigned short* Hs = Himg + (size_t)(strip * NFT32_ + fidx * 2) * 4096;
#pragma unroll
    for (int mf = 0; mf < 4; mf++)
#pragma unroll
        for (int nfl = 0; nfl < 2; nfl++) {
            const int nf = 2 * kh + nfl;
            int fl = nf * 16 + (lane & 15);
            int rl = wm * 64 + mf * 16 + ((lane >> 4) << 2);
            unsigned short* Ht = Hs + (size_t)(fl >> 5) * 4096 + ((fl & 31) >> 3) * 1024 + (fl & 7);
#pragma unroll
            for (int q = 0; q < 4; q++) {
                float g = accG[mf][nf][q], u = accU[mf][nf][q];
                float h = g * u / (1.f + __expf(-g));
                Ht[(rl + q) * 8] = f2bf(h);
            }
        }
}

// ================= GEMM2: kh-split waves, A(H) direct->regs, B(Wd) 3-deep LDS =================
__global__ __launch_bounds__(256, 3) void k_gemm2_dma(
    const unsigned short* __restrict__ Himg, const unsigned short* __restrict__ WdI,
    const int* __restrict__ slot_token, const int* __restrict__ cnt,
    const float* __restrict__ scores, float* __restrict__ y) {
    const int bid = blockIdx.x;           // 5120 = 8 xcd * 128 groups * 5 m
    const int xcd = bid & 7;
    const int j = bid >> 3;
    const int mb = j % 5;
    const int gl = j / 5;
    const int group = xcd * 128 + gl;
    const int e = group >> 6, didx = group & 63;
    const int m0 = mb * 128, d0 = didx * 64;
    if (m0 >= cnt[e]) return;
    const int strip = e * 5 + mb;

    __shared__ __align__(16) unsigned short Bd[3][4096];    // 24 KB
    __shared__ int tokS[128];
    __shared__ float scS[128];

    const int tid = threadIdx.x;
    const int lane = tid & 63, wave = tid >> 6;
    const int wm = wave & 1, kh = wave >> 1;

    if (tid < 128) {
        int t = slot_token[e * CAP_ + m0 + tid];
        tokS[tid] = t;
        scS[tid] = (t >= 0) ? scores[t] : 0.f;
    }
    __syncthreads();

    f32x4 acc[4][4];
#pragma unroll
    for (int a = 0; a < 4; a++)
#pragma unroll
        for (int b = 0; b < 4; b++) {
            f32x4 z = {0.f, 0.f, 0.f, 0.f};
            acc[a][b] = z;
        }

    const unsigned short* Hstrip = Himg + (size_t)strip * NFT32_ * 4096;
    const unsigned short* WdE = WdI + ((size_t)e * NFT32_ * 64 + didx) * 2048;
    const int WDS = 64 * 2048;
    const int afo = (lane >> 4) * 1024 + (wm * 64 + (lane & 15)) * 8;
    const int bfo = (lane >> 4) * 512 + (lane & 15) * 8;

    bf16x8 a0[4], a1[4];

#define LOADA2(T, S)                                                             \
    {                                                                            \
        const unsigned short* ab = Hstrip + (size_t)(2 * (T) + kh) * 4096 + afo; \
        _Pragma("unroll") for (int mf = 0; mf < 4; mf++)                         \
            S[mf] = *(const bf16x8*)(ab + mf * 128);                             \
    }
#define DMAB2(T, BUF)                                                            \
    {                                                                            \
        const unsigned short* bA = WdE + (size_t)(2 * (T)) * WDS;                \
        const unsigned short* bB = bA + WDS;                                     \
        _Pragma("unroll") for (int i = 0; i < 2; i++) {                          \
            const int c = wave * 2 + i;                                          \
            const unsigned short* src = (c < 4) ? (bA + c * 512) : (bB + (c - 4) * 512); \
            gload16(src + lane * 8, &Bd[BUF][c * 512]);                          \
        }                                                                        \
    }
#define MFMAS2(BUF, S)                                                           \
    {                                                                            \
        __builtin_amdgcn_s_setprio(1);                                           \
        bf16x8 bv[4];                                                            \
        _Pragma("unroll") for (int nf = 0; nf < 4; nf++)                         \
            bv[nf] = *(const bf16x8*)&Bd[BUF][kh * 2048 + bfo + nf * 128];       \
        _Pragma("unroll") for (int mf = 0; mf < 4; mf++)                         \
        _Pragma("unroll") for (int nf = 0; nf < 4; nf++)                         \
            acc[mf][nf] = __builtin_amdgcn_mfma_f32_16x16x32_bf16(S[mf], bv[nf], acc[mf][nf], 0, 0, 0); \
        __builtin_amdgcn_s_setprio(0);                                           \
    }
#define G2IT(T, CS, NS, WN, HA, HB)                                              \
    {                                                                            \
        WAITVN(WN);                                                              \
        SBAR;                                                                    \
        if (HA) { LOADA2((T) + 1, NS) }                                          \
        if (HB) { DMAB2((T) + 2, ((T) + 2) % 3) }                                \
        SCHED0;                                                                  \
        MFMAS2((T) % 3, CS)                                                      \
    }

    LOADA2(0, a0)
    SCHED0;
    DMAB2(0, 0)
    DMAB2(1, 1)
    SCHED0;

    G2IT(0, a0, a1, 2, 1, 1)
    G2IT(1, a1, a0, 2, 1, 1)
    G2IT(2, a0, a1, 2, 1, 1)
    G2IT(3, a1, a0, 2, 1, 1)
    G2IT(4, a0, a1, 2, 1, 1)
    G2IT(5, a1, a0, 2, 1, 1)
    G2IT(6, a0, a1, 2, 1, 1)
    G2IT(7, a1, a0, 2, 1, 1)
    G2IT(8, a0, a1, 2, 1, 1)
    G2IT(9, a1, a0, 2, 1, 0)
    G2IT(10, a0, a1, 0, 0, 0)
#undef G2IT
#undef MFMAS2
#undef DMAB2
#undef LOADA2

    // ---- cross-wave K-half reduction (Bd reused, 16 KB per mf-half round) ----
    {
        float* red = (float*)(&Bd[0][0]);
#pragma unroll
        for (int mh = 0; mh < 2; mh++) {
            __syncthreads();
#pragma unroll
            for (int mfl = 0; mfl < 2; mfl++)
#pragma unroll
                for (int nfl = 0; nfl < 2; nfl++)
                    *(f32x4*)&red[((((wm * 2 + (1 - kh)) * 2 + mfl) * 2 + nfl)) * 256 + lane * 4] =
                        acc[mh * 2 + mfl][2 * (1 - kh) + nfl];
            __syncthreads();
#pragma unroll
            for (int mfl = 0; mfl < 2; mfl++)
#pragma unroll
                for (int nfl = 0; nfl < 2; nfl++) {
                    f32x4 p = *(const f32x4*)&red[((((wm * 2 + kh) * 2 + mfl) * 2 + nfl)) * 256 + lane * 4];
                    acc[mh * 2 + mfl][2 * kh + nfl] += p;
                }
        }
    }

    // ---- epilogue: scale by score, scatter; wave owns cols d0+(2kh+nfl)*16 ----
#pragma unroll
    for (int mf = 0; mf < 4; mf++)
#pragma unroll
        for (int nfl = 0; nfl < 2; nfl++) {
            const int nf = 2 * kh + nfl;
            int d = d0 + nf * 16 + (lane & 15);
            int rowb = wm * 64 + mf * 16 + ((lane >> 4) << 2);
#pragma unroll
            for (int q = 0; q < 4; q++) {
                int row = rowb + q;
                int t = tokS[row];
                if (t >= 0) y[(size_t)t * D_ + d] = acc[mf][nf][q] * scS[row];
            }
        }
}

extern "C" void kernel_launch(void* const* d_in, const int* in_sizes, int n_in,
                              void* d_out, int out_size, void* d_ws, size_t ws_size,
                              hipStream_t stream) {
    const float* x   = (const float*)d_in[0];
    const int*   idx = (const int*)d_in[1];
    const float* sc  = (const float*)d_in[2];
    const float* Wg  = (const float*)d_in[3];
    const float* Wu  = (const float*)d_in[4];
    const float* Wd  = (const float*)d_in[5];
    float* y = (float*)d_out;

    char* ws = (char*)d_ws;
    int* slot_token = (int*)ws;                              // E*CAP ints
    int* row_of     = (int*)(ws + 40960);                    // N ints
    int* cnt        = (int*)(ws + 40960 + 32768);            // E ints
    const size_t hoff   = 131072;
    const size_t hbytes = (size_t)80 * NFT32_ * 8192;        // 14,417,920 (H image)
    unsigned short* Himg = (unsigned short*)(ws + hoff);
    const size_t aoff   = hoff + hbytes;
    const size_t abytes = (size_t)80 * NKT32_ * 8192;        // 83,886,080 (A image)
    unsigned short* Aimg = (unsigned short*)(ws + aoff);
    const size_t guoff   = aoff + abytes;
    const size_t gubytes = (size_t)E_ * NKT32_ * NFT_ * 8192; // 184,549,376 (Wg+Wu image)
    unsigned short* WguI = (unsigned short*)(ws + guoff);
    const size_t wdoff   = guoff + gubytes;
    unsigned short* WdI  = (unsigned short*)(ws + wdoff);    // 92,274,688 (Wd image)

    k_dispatch<<<1, 256, 0, stream>>>(idx, slot_token, row_of, cnt);
    k_zero_dropped<<<128, 256, 0, stream>>>(row_of, y);
    k_gather<<<dim3(16, 80), 256, 0, stream>>>(x, slot_token, Aimg);
    k_wprep_gu<<<dim3(NFT_, 64, E_), 256, 0, stream>>>(Wg, Wu, WguI);
    k_wprep_d<<<dim3(64, NFT_, E_), 256, 0, stream>>>(Wd, WdI);
    k_gemm1_dma<<<880, 256, 0, stream>>>(Aimg, WguI, cnt, Himg);
    k_gemm2_dma<<<5120, 256, 0, stream>>>(Himg, WdI, slot_token, cnt, sc, y);
}

// Round 12
// 510.116 us; speedup vs baseline: 2.1706x; 2.1706x over previous
//
#include <hip/hip_runtime.h>
#include <hip/hip_bf16.h>

#define E_ 16
#define D_ 4096
#define F_ 688
#define N_ 8192
#define CAP_ 640     // int(1.25 * 8192 / 16)
#define NFT_ 11      // 64-f tiles
#define NKT32_ 128   // D/32 k-tiles
#define NFT32_ 22    // ceil(F/32) f-tiles (pad to 704)

typedef __attribute__((ext_vector_type(8))) short bf16x8;
typedef __attribute__((ext_vector_type(4))) float f32x4;
typedef __attribute__((ext_vector_type(4))) float fvec4;
typedef __attribute__((ext_vector_type(4))) unsigned short usvec4;
typedef __attribute__((ext_vector_type(8))) unsigned short usvec8;

__device__ __forceinline__ unsigned short f2bf(float f) {
    __hip_bfloat16 h = __float2bfloat16(f);
    return __builtin_bit_cast(unsigned short, h);
}
// async global->LDS, 16B per lane
__device__ __forceinline__ void gload16(const unsigned short* g, unsigned short* l) {
    __builtin_amdgcn_global_load_lds(
        (const __attribute__((address_space(1))) unsigned int*)g,
        (__attribute__((address_space(3))) unsigned int*)l, 16, 0, 0);
}

#define WAITVN(N) asm volatile("s_waitcnt vmcnt(" #N ")" ::: "memory")
#define SBAR      __builtin_amdgcn_s_barrier()
#define SCHED0    __builtin_amdgcn_sched_barrier(0)

// Tile layouts (k-major, conflict-free):
//   A-tile (128 rows x 32 k):  [kgroup 4][row 128][8 bf16] = 4096 elems
//   B-tile ( 64 rows x 32 k):  [kgroup 4][row  64][8 bf16] = 2048 elems
// Waves are (wm, kh): each wave owns 64 rows x ALL cols x half of each BK=64
// step -> A read exactly once per block. K-halves reduced via LDS at epilogue.
// RULE #20: every acc[] index below is a compile-time constant (kh handled by
// wave-uniform branch duplication), so acc stays in VGPRs.

// ---------------- dispatch ----------------
__global__ void k_dispatch(const int* __restrict__ idx,
                           int* __restrict__ slot_token,
                           int* __restrict__ row_of,
                           int* __restrict__ cnt) {
    __shared__ int hist[256][E_];
    const int t = threadIdx.x;
#pragma unroll
    for (int e = 0; e < E_; e++) hist[t][e] = 0;
    __syncthreads();
    const int base = t * (N_ / 256);
    for (int j = 0; j < N_ / 256; j++) {
        int e = idx[base + j];
        hist[t][e]++;
    }
    __syncthreads();
    if (t < E_) {
        int run = 0;
        for (int i = 0; i < 256; i++) { int v = hist[i][t]; hist[i][t] = run; run += v; }
        cnt[t] = run < CAP_ ? run : CAP_;
    }
    for (int s = t; s < E_ * CAP_; s += 256) slot_token[s] = -1;
    __syncthreads();
    for (int j = 0; j < N_ / 256; j++) {
        int i = base + j;
        int e = idx[i];
        int p = hist[t][e]++;
        if (p < CAP_) { slot_token[e * CAP_ + p] = i; row_of[i] = e * CAP_ + p; }
        else          { row_of[i] = -1; }
    }
}

__global__ void k_zero_dropped(const int* __restrict__ row_of, float* __restrict__ y) {
    for (int i = blockIdx.x; i < N_; i += gridDim.x) {
        if (row_of[i] >= 0) continue;
        fvec4* yp = (fvec4*)(y + (size_t)i * D_);
        fvec4 z = {0.f, 0.f, 0.f, 0.f};
        for (int c = threadIdx.x; c < D_ / 4; c += 256) yp[c] = z;
    }
}

// ---------------- gather x -> Aimg (k-major 32-k tiles, bf16) ----------------
__global__ void k_gather(const float* __restrict__ x, const int* __restrict__ slot_token,
                         unsigned short* __restrict__ Aimg) {
    const int strip = blockIdx.y;       // 0..79  (= e*5 + mb)
    const int kg = blockIdx.x;          // 0..15  (8 k-tiles each)
    const int t = threadIdx.x;
    const int r = t >> 1, h = t & 1;
    const int tok = slot_token[strip * 128 + r];
#pragma unroll
    for (int i = 0; i < 8; i++) {
        const int kt = kg * 8 + i;
        unsigned short* dst = Aimg + ((size_t)strip * NKT32_ + kt) * 4096;
        usvec8 p0, p1;
        if (tok < 0) {
            usvec8 z = {0, 0, 0, 0, 0, 0, 0, 0};
            p0 = z; p1 = z;
        } else {
            const float* src = x + (size_t)tok * D_ + kt * 32 + h * 16;
            fvec4 a = *(const fvec4*)(src);
            fvec4 b = *(const fvec4*)(src + 4);
            fvec4 c = *(const fvec4*)(src + 8);
            fvec4 d = *(const fvec4*)(src + 12);
            usvec8 q0 = {f2bf(a[0]), f2bf(a[1]), f2bf(a[2]), f2bf(a[3]),
                         f2bf(b[0]), f2bf(b[1]), f2bf(b[2]), f2bf(b[3])};
            usvec8 q1 = {f2bf(c[0]), f2bf(c[1]), f2bf(c[2]), f2bf(c[3]),
                         f2bf(d[0]), f2bf(d[1]), f2bf(d[2]), f2bf(d[3])};
            p0 = q0; p1 = q1;
        }
        *(usvec8*)&dst[(2 * h) * 1024 + r * 8]     = p0;
        *(usvec8*)&dst[(2 * h + 1) * 1024 + r * 8] = p1;
    }
}

// ---------------- wprep: Wg,Wu -> [e][kt32][ft][G 2048 | U 2048] ----------------
__global__ void k_wprep_gu(const float* __restrict__ Wg, const float* __restrict__ Wu,
                           unsigned short* __restrict__ img) {
    const int ft = blockIdx.x, kt = blockIdx.y, e = blockIdx.z;   // kt: 64-k block
    const int tid = threadIdx.x;
    const int f4 = (tid & 15) * 4, kq4 = (tid >> 4) * 4;
    const int gf = ft * 64 + f4;
    const bool v = gf < F_;
    const fvec4 fz = {0.f, 0.f, 0.f, 0.f};
    fvec4 g[4], u[4];
#pragma unroll
    for (int r = 0; r < 4; r++) {
        size_t off = (size_t)e * D_ * F_ + (size_t)(kt * 64 + kq4 + r) * F_ + gf;
        g[r] = v ? *(const fvec4*)(Wg + off) : fz;
        u[r] = v ? *(const fvec4*)(Wu + off) : fz;
    }
    const int t32 = kq4 >> 5, kl = kq4 & 31;
    unsigned short* dst = img + ((size_t)(e * NKT32_ + kt * 2 + t32) * NFT_ + ft) * 4096;
    const int ubase = (kl >> 3) * 512 + (kl & 7);
#pragma unroll
    for (int i = 0; i < 4; i++) {
        usvec4 pg = {f2bf(g[0][i]), f2bf(g[1][i]), f2bf(g[2][i]), f2bf(g[3][i])};
        usvec4 pu = {f2bf(u[0][i]), f2bf(u[1][i]), f2bf(u[2][i]), f2bf(u[3][i])};
        *(usvec4*)&dst[ubase + (f4 + i) * 8]        = pg;
        *(usvec4*)&dst[2048 + ubase + (f4 + i) * 8] = pu;
    }
}

// ---------------- wprep: Wd -> [e][kt32(22)][dt(64)][2048] ----------------
__global__ void k_wprep_d(const float* __restrict__ Wd, unsigned short* __restrict__ img) {
    const int dt = blockIdx.x, kt = blockIdx.y, e = blockIdx.z;   // kt: 64-k block (0..10)
    const int tid = threadIdx.x;
    const int d4 = (tid & 15) * 4, kq4 = (tid >> 4) * 4;
    const int gd = dt * 64 + d4;
    const fvec4 fz = {0.f, 0.f, 0.f, 0.f};
    fvec4 b[4];
#pragma unroll
    for (int r = 0; r < 4; r++) {
        int krow = kt * 64 + kq4 + r;
        b[r] = (krow < F_) ? *(const fvec4*)(Wd + (size_t)e * F_ * D_ + (size_t)krow * D_ + gd) : fz;
    }
    const int t32 = kq4 >> 5, kl = kq4 & 31;
    unsigned short* dst = img + ((size_t)(e * NFT32_ + kt * 2 + t32) * 64 + dt) * 2048;
    const int ubase = (kl >> 3) * 512 + (kl & 7);
#pragma unroll
    for (int i = 0; i < 4; i++) {
        usvec4 p = {f2bf(b[0][i]), f2bf(b[1][i]), f2bf(b[2][i]), f2bf(b[3][i])};
        *(usvec4*)&dst[ubase + (d4 + i) * 8] = p;
    }
}

// ================= GEMM1: kh-split waves, A direct->regs, B 3-deep LDS DMA =================
__global__ __launch_bounds__(256, 2) void k_gemm1_dma(
    const unsigned short* __restrict__ Aimg, const unsigned short* __restrict__ Wgu,
    const int* __restrict__ cnt, unsigned short* __restrict__ Himg) {
    const int bid = blockIdx.x;           // 880 = 8 xcd * 22 groups * 5 m
    const int xcd = bid & 7;
    const int j = bid >> 3;
    const int mb = j % 5;
    const int gl = j / 5;
    const int group = xcd * 22 + gl;      // 0..175
    const int e = group / NFT_, fidx = group % NFT_;
    const int m0 = mb * 128;
    if (m0 >= cnt[e]) return;
    const int strip = e * 5 + mb;

    __shared__ __align__(16) unsigned short Bgu[3][8192];   // 48 KB

    const int tid = threadIdx.x;
    const int lane = tid & 63, wave = tid >> 6;
    const int wm = wave & 1, kh = wave >> 1;

    f32x4 accG[4][4], accU[4][4];
#pragma unroll
    for (int a = 0; a < 4; a++)
#pragma unroll
        for (int b = 0; b < 4; b++) {
            f32x4 z = {0.f, 0.f, 0.f, 0.f};
            accG[a][b] = z; accU[a][b] = z;
        }

    const unsigned short* Astrip = Aimg + (size_t)strip * NKT32_ * 4096;
    const unsigned short* WguE = Wgu + ((size_t)e * NKT32_ * NFT_ + fidx) * 4096;
    const int GUS = NFT_ * 4096;
    const int afo = (lane >> 4) * 1024 + (wm * 64 + (lane & 15)) * 8;
    const int bfo = (lane >> 4) * 512 + (lane & 15) * 8;

    bf16x8 a0[4], a1[4];

#define LOADA1(T, S)                                                             \
    {                                                                            \
        const unsigned short* ab = Astrip + (size_t)(2 * (T) + kh) * 4096 + afo; \
        _Pragma("unroll") for (int mf = 0; mf < 4; mf++)                         \
            S[mf] = *(const bf16x8*)(ab + mf * 128);                             \
    }
#define DMAB1(T, BUF)                                                            \
    {                                                                            \
        const unsigned short* bA = WguE + (size_t)(2 * (T)) * GUS;               \
        const unsigned short* bB = bA + GUS;                                     \
        _Pragma("unroll") for (int i = 0; i < 4; i++) {                          \
            const int c = wave * 4 + i;                                          \
            const unsigned short* src = (c < 8) ? (bA + c * 512) : (bB + (c - 8) * 512); \
            gload16(src + lane * 8, &Bgu[BUF][c * 512]);                         \
        }                                                                        \
    }
#define MFMAS1(BUF, S)                                                           \
    {                                                                            \
        __builtin_amdgcn_s_setprio(1);                                           \
        bf16x8 bg[4], bu[4];                                                     \
        _Pragma("unroll") for (int nf = 0; nf < 4; nf++) {                       \
            bg[nf] = *(const bf16x8*)&Bgu[BUF][kh * 4096 + bfo + nf * 128];      \
            bu[nf] = *(const bf16x8*)&Bgu[BUF][kh * 4096 + 2048 + bfo + nf * 128]; \
        }                                                                        \
        _Pragma("unroll") for (int mf = 0; mf < 4; mf++)                         \
        _Pragma("unroll") for (int nf = 0; nf < 4; nf++) {                       \
            accG[mf][nf] = __builtin_amdgcn_mfma_f32_16x16x32_bf16(S[mf], bg[nf], accG[mf][nf], 0, 0, 0); \
            accU[mf][nf] = __builtin_amdgcn_mfma_f32_16x16x32_bf16(S[mf], bu[nf], accU[mf][nf], 0, 0, 0); \
        }                                                                        \
        __builtin_amdgcn_s_setprio(0);                                           \
    }
#define G1IT(T, CS, NS, WN, HA, HB)                                              \
    {                                                                            \
        WAITVN(WN);                                                              \
        SBAR;                                                                    \
        if (HA) { LOADA1((T) + 1, NS) }                                          \
        if (HB) { DMAB1((T) + 2, ((T) + 2) % 3) }                                \
        SCHED0;                                                                  \
        MFMAS1((T) % 3, CS)                                                      \
    }

    LOADA1(0, a0)
    SCHED0;
    DMAB1(0, 0)
    DMAB1(1, 1)
    SCHED0;

    for (int m = 0; m < 31; m++) {
        G1IT(2 * m,     a0, a1, 4, 1, 1)
        G1IT(2 * m + 1, a1, a0, 4, 1, 1)
    }
    G1IT(62, a0, a1, 4, 1, 0)
    G1IT(63, a1, a0, 0, 0, 0)
#undef G1IT
#undef MFMAS1
#undef DMAB1
#undef LOADA1

    // ---- cross-wave K-half reduction; ALL acc indices compile-time (rule #20) ----
    {
        float* red = (float*)(&Bgu[0][0]);
#define RED1(ACC)                                                                \
    {                                                                            \
        __syncthreads();                                                         \
        if (kh == 0) {                                                           \
            _Pragma("unroll") for (int mf = 0; mf < 4; mf++)                     \
            _Pragma("unroll") for (int nfl = 0; nfl < 2; nfl++)                  \
                *(f32x4*)&red[(((wm * 2 + 1) * 4 + mf) * 2 + nfl) * 256 + lane * 4] = ACC[mf][2 + nfl]; \
        } else {                                                                 \
            _Pragma("unroll") for (int mf = 0; mf < 4; mf++)                     \
            _Pragma("unroll") for (int nfl = 0; nfl < 2; nfl++)                  \
                *(f32x4*)&red[(((wm * 2 + 0) * 4 + mf) * 2 + nfl) * 256 + lane * 4] = ACC[mf][0 + nfl]; \
        }                                                                        \
        __syncthreads();                                                         \
        if (kh == 0) {                                                           \
            _Pragma("unroll") for (int mf = 0; mf < 4; mf++)                     \
            _Pragma("unroll") for (int nfl = 0; nfl < 2; nfl++) {                \
                f32x4 p = *(const f32x4*)&red[(((wm * 2 + 0) * 4 + mf) * 2 + nfl) * 256 + lane * 4]; \
                ACC[mf][0 + nfl] += p;                                           \
            }                                                                    \
        } else {                                                                 \
            _Pragma("unroll") for (int mf = 0; mf < 4; mf++)                     \
            _Pragma("unroll") for (int nfl = 0; nfl < 2; nfl++) {                \
                f32x4 p = *(const f32x4*)&red[(((wm * 2 + 1) * 4 + mf) * 2 + nfl) * 256 + lane * 4]; \
                ACC[mf][2 + nfl] += p;                                           \
            }                                                                    \
        }                                                                        \
    }
        RED1(accG)
        RED1(accU)
#undef RED1
    }

    // ---- epilogue: fused SwiGLU -> Himg; wave kh keeps cols {2kh,2kh+1} ----
    unsigned short* Hs = Himg + (size_t)(strip * NFT32_ + fidx * 2) * 4096;
#define EPI1(NB)                                                                 \
    _Pragma("unroll") for (int mf = 0; mf < 4; mf++)                             \
    _Pragma("unroll") for (int nfl = 0; nfl < 2; nfl++) {                        \
        int fl = (NB + nfl) * 16 + (lane & 15);                                  \
        int rl = wm * 64 + mf * 16 + ((lane >> 4) << 2);                         \
        unsigned short* Ht = Hs + (size_t)(fl >> 5) * 4096 + ((fl & 31) >> 3) * 1024 + (fl & 7); \
        _Pragma("unroll") for (int q = 0; q < 4; q++) {                          \
            float g = accG[mf][NB + nfl][q], u = accU[mf][NB + nfl][q];          \
            float h = g * u / (1.f + __expf(-g));                                \
            Ht[(rl + q) * 8] = f2bf(h);                                          \
        }                                                                        \
    }
    if (kh == 0) { EPI1(0) } else { EPI1(2) }
#undef EPI1
}

// ================= GEMM2: kh-split waves, A(H) direct->regs, B(Wd) 3-deep LDS =================
__global__ __launch_bounds__(256, 3) void k_gemm2_dma(
    const unsigned short* __restrict__ Himg, const unsigned short* __restrict__ WdI,
    const int* __restrict__ slot_token, const int* __restrict__ cnt,
    const float* __restrict__ scores, float* __restrict__ y) {
    const int bid = blockIdx.x;           // 5120 = 8 xcd * 128 groups * 5 m
    const int xcd = bid & 7;
    const int j = bid >> 3;
    const int mb = j % 5;
    const int gl = j / 5;
    const int group = xcd * 128 + gl;
    const int e = group >> 6, didx = group & 63;
    const int m0 = mb * 128, d0 = didx * 64;
    if (m0 >= cnt[e]) return;
    const int strip = e * 5 + mb;

    __shared__ __align__(16) unsigned short Bd[3][4096];    // 24 KB
    __shared__ int tokS[128];
    __shared__ float scS[128];

    const int tid = threadIdx.x;
    const int lane = tid & 63, wave = tid >> 6;
    const int wm = wave & 1, kh = wave >> 1;

    if (tid < 128) {
        int t = slot_token[e * CAP_ + m0 + tid];
        tokS[tid] = t;
        scS[tid] = (t >= 0) ? scores[t] : 0.f;
    }
    __syncthreads();

    f32x4 acc[4][4];
#pragma unroll
    for (int a = 0; a < 4; a++)
#pragma unroll
        for (int b = 0; b < 4; b++) {
            f32x4 z = {0.f, 0.f, 0.f, 0.f};
            acc[a][b] = z;
        }

    const unsigned short* Hstrip = Himg + (size_t)strip * NFT32_ * 4096;
    const unsigned short* WdE = WdI + ((size_t)e * NFT32_ * 64 + didx) * 2048;
    const int WDS = 64 * 2048;
    const int afo = (lane >> 4) * 1024 + (wm * 64 + (lane & 15)) * 8;
    const int bfo = (lane >> 4) * 512 + (lane & 15) * 8;

    bf16x8 a0[4], a1[4];

#define LOADA2(T, S)                                                             \
    {                                                                            \
        const unsigned short* ab = Hstrip + (size_t)(2 * (T) + kh) * 4096 + afo; \
        _Pragma("unroll") for (int mf = 0; mf < 4; mf++)                         \
            S[mf] = *(const bf16x8*)(ab + mf * 128);                             \
    }
#define DMAB2(T, BUF)                                                            \
    {                                                                            \
        const unsigned short* bA = WdE + (size_t)(2 * (T)) * WDS;                \
        const unsigned short* bB = bA + WDS;                                     \
        _Pragma("unroll") for (int i = 0; i < 2; i++) {                          \
            const int c = wave * 2 + i;                                          \
            const unsigned short* src = (c < 4) ? (bA + c * 512) : (bB + (c - 4) * 512); \
            gload16(src + lane * 8, &Bd[BUF][c * 512]);                          \
        }                                                                        \
    }
#define MFMAS2(BUF, S)                                                           \
    {                                                                            \
        __builtin_amdgcn_s_setprio(1);                                           \
        bf16x8 bv[4];                                                            \
        _Pragma("unroll") for (int nf = 0; nf < 4; nf++)                         \
            bv[nf] = *(const bf16x8*)&Bd[BUF][kh * 2048 + bfo + nf * 128];       \
        _Pragma("unroll") for (int mf = 0; mf < 4; mf++)                         \
        _Pragma("unroll") for (int nf = 0; nf < 4; nf++)                         \
            acc[mf][nf] = __builtin_amdgcn_mfma_f32_16x16x32_bf16(S[mf], bv[nf], acc[mf][nf], 0, 0, 0); \
        __builtin_amdgcn_s_setprio(0);                                           \
    }
#define G2IT(T, CS, NS, WN, HA, HB)                                              \
    {                                                                            \
        WAITVN(WN);                                                              \
        SBAR;                                                                    \
        if (HA) { LOADA2((T) + 1, NS) }                                          \
        if (HB) { DMAB2((T) + 2, ((T) + 2) % 3) }                                \
        SCHED0;                                                                  \
        MFMAS2((T) % 3, CS)                                                      \
    }

    LOADA2(0, a0)
    SCHED0;
    DMAB2(0, 0)
    DMAB2(1, 1)
    SCHED0;

    G2IT(0, a0, a1, 2, 1, 1)
    G2IT(1, a1, a0, 2, 1, 1)
    G2IT(2, a0, a1, 2, 1, 1)
    G2IT(3, a1, a0, 2, 1, 1)
    G2IT(4, a0, a1, 2, 1, 1)
    G2IT(5, a1, a0, 2, 1, 1)
    G2IT(6, a0, a1, 2, 1, 1)
    G2IT(7, a1, a0, 2, 1, 1)
    G2IT(8, a0, a1, 2, 1, 1)
    G2IT(9, a1, a0, 2, 1, 0)
    G2IT(10, a0, a1, 0, 0, 0)
#undef G2IT
#undef MFMAS2
#undef DMAB2
#undef LOADA2

    // ---- cross-wave K-half reduction; compile-time indices only ----
    {
        float* red = (float*)(&Bd[0][0]);
#define RED2(MH)                                                                 \
    {                                                                            \
        __syncthreads();                                                         \
        if (kh == 0) {                                                           \
            _Pragma("unroll") for (int mfl = 0; mfl < 2; mfl++)                  \
            _Pragma("unroll") for (int nfl = 0; nfl < 2; nfl++)                  \
                *(f32x4*)&red[((((wm * 2 + 1) * 2 + mfl) * 2 + nfl)) * 256 + lane * 4] = acc[(MH) * 2 + mfl][2 + nfl]; \
        } else {                                                                 \
            _Pragma("unroll") for (int mfl = 0; mfl < 2; mfl++)                  \
            _Pragma("unroll") for (int nfl = 0; nfl < 2; nfl++)                  \
                *(f32x4*)&red[((((wm * 2 + 0) * 2 + mfl) * 2 + nfl)) * 256 + lane * 4] = acc[(MH) * 2 + mfl][0 + nfl]; \
        }                                                                        \
        __syncthreads();                                                         \
        if (kh == 0) {                                                           \
            _Pragma("unroll") for (int mfl = 0; mfl < 2; mfl++)                  \
            _Pragma("unroll") for (int nfl = 0; nfl < 2; nfl++) {                \
                f32x4 p = *(const f32x4*)&red[((((wm * 2 + 0) * 2 + mfl) * 2 + nfl)) * 256 + lane * 4]; \
                acc[(MH) * 2 + mfl][0 + nfl] += p;                               \
            }                                                                    \
        } else {                                                                 \
            _Pragma("unroll") for (int mfl = 0; mfl < 2; mfl++)                  \
            _Pragma("unroll") for (int nfl = 0; nfl < 2; nfl++) {                \
                f32x4 p = *(const f32x4*)&red[((((wm * 2 + 1) * 2 + mfl) * 2 + nfl)) * 256 + lane * 4]; \
                acc[(MH) * 2 + mfl][2 + nfl] += p;                               \
            }                                                                    \
        }                                                                        \
    }
        RED2(0)
        RED2(1)
#undef RED2
    }

    // ---- epilogue: scale by score, scatter; wave kh keeps cols d0+{2kh,2kh+1}*16 ----
#define EPI2(NB)                                                                 \
    _Pragma("unroll") for (int mf = 0; mf < 4; mf++)                             \
    _Pragma("unroll") for (int nfl = 0; nfl < 2; nfl++) {                        \
        int d = d0 + (NB + nfl) * 16 + (lane & 15);                              \
        int rowb = wm * 64 + mf * 16 + ((lane >> 4) << 2);                       \
        _Pragma("unroll") for (int q = 0; q < 4; q++) {                          \
            int row = rowb + q;                                                  \
            int t = tokS[row];                                                   \
            if (t >= 0) y[(size_t)t * D_ + d] = acc[mf][NB + nfl][q] * scS[row]; \
        }                                                                        \
    }
    if (kh == 0) { EPI2(0) } else { EPI2(2) }
#undef EPI2
}

extern "C" void kernel_launch(void* const* d_in, const int* in_sizes, int n_in,
                              void* d_out, int out_size, void* d_ws, size_t ws_size,
                              hipStream_t stream) {
    const float* x   = (const float*)d_in[0];
    const int*   idx = (const int*)d_in[1];
    const float* sc  = (const float*)d_in[2];
    const float* Wg  = (const float*)d_in[3];
    const float* Wu  = (const float*)d_in[4];
    const float* Wd  = (const float*)d_in[5];
    float* y = (float*)d_out;

    char* ws = (char*)d_ws;
    int* slot_token = (int*)ws;                              // E*CAP ints
    int* row_of     = (int*)(ws + 40960);                    // N ints
    int* cnt        = (int*)(ws + 40960 + 32768);            // E ints
    const size_t hoff   = 131072;
    const size_t hbytes = (size_t)80 * NFT32_ * 8192;        // 14,417,920 (H image)
    unsigned short* Himg = (unsigned short*)(ws + hoff);
    const size_t aoff   = hoff + hbytes;
    const size_t abytes = (size_t)80 * NKT32_ * 8192;        // 83,886,080 (A image)
    unsigned short* Aimg = (unsigned short*)(ws + aoff);
    const size_t guoff   = aoff + abytes;
    const size_t gubytes = (size_t)E_ * NKT32_ * NFT_ * 8192; // 184,549,376 (Wg+Wu image)
    unsigned short* WguI = (unsigned short*)(ws + guoff);
    const size_t wdoff   = guoff + gubytes;
    unsigned short* WdI  = (unsigned short*)(ws + wdoff);    // 92,274,688 (Wd image)

    k_dispatch<<<1, 256, 0, stream>>>(idx, slot_token, row_of, cnt);
    k_zero_dropped<<<128, 256, 0, stream>>>(row_of, y);
    k_gather<<<dim3(16, 80), 256, 0, stream>>>(x, slot_token, Aimg);
    k_wprep_gu<<<dim3(NFT_, 64, E_), 256, 0, stream>>>(Wg, Wu, WguI);
    k_wprep_d<<<dim3(64, NFT_, E_), 256, 0, stream>>>(Wd, WdI);
    k_gemm1_dma<<<880, 256, 0, stream>>>(Aimg, WguI, cnt, Himg);
    k_gemm2_dma<<<5120, 256, 0, stream>>>(Himg, WdI, slot_token, cnt, sc, y);
}